// Round 3
// baseline (190.028 us; speedup 1.0000x reference)
//
#include <hip/hip_runtime.h>
#include <hip/hip_bf16.h>

// Problem constants (fixed by the reference).
constexpr int N_NODES = 50000;
constexpr int IN_F    = 128;
constexpr long E_EDGES = 800000;
constexpr int EDGE_F  = 32;
constexpr int H_HEADS = 4;
constexpr int C_CH    = 32;
constexpr int HC      = 128;   // H*C
constexpr float NEG_SLOPE = 0.2f;
constexpr float EPS = 1e-16f;
constexpr int NB_SCAN = (N_NODES + 255) / 256;   // 196
constexpr int NB_HIST = (int)((E_EDGES + 255) / 256); // 3125
constexpr float SM_SHIFT = 12.0f;  // fixed softmax shift (shift-invariant; logits << 87)

typedef __attribute__((ext_vector_type(8))) short bf16x8;
typedef __attribute__((ext_vector_type(4))) float f32x4;

__device__ __forceinline__ unsigned short f2b(float f) {
    __hip_bfloat16 h = __float2bfloat16(f);   // RNE
    return *reinterpret_cast<unsigned short*>(&h);
}
__device__ __forceinline__ float b2f_lo(unsigned v) { return __uint_as_float(v << 16); }
__device__ __forceinline__ float b2f_hi(unsigned v) { return __uint_as_float(v & 0xffff0000u); }

// ---------------------------------------------------------------------------
// prep kernel: blocks 0..31 convert W_gat/W_skip -> wcat bf16 [256][128];
// block 32 computes weff[h,f] = sum_c W_edge[h*32+c,f]*att_edge[h,c];
// blocks 33.. histogram dst -> counts AND record per-edge rank (return value).
// ---------------------------------------------------------------------------
__global__ __launch_bounds__(256) void prep_kernel(
    const float* __restrict__ Wg, const float* __restrict__ Ws,
    unsigned short* __restrict__ wcat, const float* __restrict__ We,
    const float* __restrict__ att_edge, float* __restrict__ weff,
    const int* __restrict__ dst, int* __restrict__ counts,
    int* __restrict__ rank)
{
    const int b = blockIdx.x, t = threadIdx.x;
    if (b < 32) {
        int i = (b * 256 + t) * 4;   // 0 .. 32764
        const float* srcp = (i < 16384) ? (Wg + i) : (Ws + i - 16384);
        float4 v = *(const float4*)srcp;
        ushort4 o;
        o.x = f2b(v.x); o.y = f2b(v.y); o.z = f2b(v.z); o.w = f2b(v.w);
        *(ushort4*)&wcat[i] = o;
    } else if (b == 32) {
        if (t < 128) {
            int h = t >> 5, f = t & 31;
            float acc = 0.f;
#pragma unroll
            for (int c = 0; c < C_CH; ++c)
                acc = fmaf(We[(h * C_CH + c) * EDGE_F + f], att_edge[h * C_CH + c], acc);
            weff[t] = acc;
        }
    } else {
        long e = (long)(b - 33) * 256 + t;
        if (e < E_EDGES) rank[e] = atomicAdd(&counts[dst[e]], 1);
    }
}

// ---------------------------------------------------------------------------
// Kernel 1: MFMA GEMM.  [N x 128] @ [256 x 128]^T; cols 0..127 -> x (bf16),
// cols 128..255 -> out (+bias, fp32).  Block: 64 nodes x 256 cols, 4 waves.
// ---------------------------------------------------------------------------
__global__ __launch_bounds__(256) void mfma_gemm_kernel(
    const float* __restrict__ nf, const unsigned short* __restrict__ wcat,
    const float* __restrict__ bias, unsigned short* __restrict__ xb,
    float* __restrict__ out)
{
    const int t  = threadIdx.x;
    const int w  = t >> 6;          // wave id: cols w*64 ..
    const int l  = t & 63;
    const int lr = l & 15;
    const int lk = l >> 4;
    const int n0 = blockIdx.x * 64;

    // B frags: 4 col-frags x 4 k-steps, 16B each -> 64 VGPRs
    bf16x8 bfr[4][4];
#pragma unroll
    for (int nfr = 0; nfr < 4; ++nfr)
#pragma unroll
        for (int ks = 0; ks < 4; ++ks)
            bfr[nfr][ks] = *(const bf16x8*)&wcat[(w * 64 + nfr * 16 + lr) * 128 + ks * 32 + lk * 8];

    f32x4 acc[4][4];
#pragma unroll
    for (int mf = 0; mf < 4; ++mf)
#pragma unroll
        for (int nfr = 0; nfr < 4; ++nfr)
            acc[mf][nfr] = (f32x4){0.f, 0.f, 0.f, 0.f};

#pragma unroll
    for (int ks = 0; ks < 4; ++ks) {
        bf16x8 afr[4];
#pragma unroll
        for (int mf = 0; mf < 4; ++mf) {
            int row = n0 + mf * 16 + lr;
            row = row < N_NODES ? row : N_NODES - 1;   // clamp (tail rows discarded)
            const float* ap = nf + (size_t)row * IN_F + ks * 32 + lk * 8;
            float4 a0 = *(const float4*)ap;
            float4 a1 = *(const float4*)(ap + 4);
            bf16x8 f;
            f[0] = (short)f2b(a0.x); f[1] = (short)f2b(a0.y);
            f[2] = (short)f2b(a0.z); f[3] = (short)f2b(a0.w);
            f[4] = (short)f2b(a1.x); f[5] = (short)f2b(a1.y);
            f[6] = (short)f2b(a1.z); f[7] = (short)f2b(a1.w);
            afr[mf] = f;
        }
#pragma unroll
        for (int mf = 0; mf < 4; ++mf)
#pragma unroll
            for (int nfr = 0; nfr < 4; ++nfr)
                acc[mf][nfr] = __builtin_amdgcn_mfma_f32_16x16x32_bf16(
                    afr[mf], bfr[nfr][ks], acc[mf][nfr], 0, 0, 0);
    }

    // epilogue: cols <128 -> x (bf16) ; cols >=128 -> out + bias (fp32)
#pragma unroll
    for (int nfr = 0; nfr < 4; ++nfr) {
        const int gc = w * 64 + nfr * 16 + lr;
        if (gc < HC) {
#pragma unroll
            for (int mf = 0; mf < 4; ++mf)
#pragma unroll
                for (int r = 0; r < 4; ++r) {
                    int m = n0 + mf * 16 + lk * 4 + r;
                    if (m < N_NODES) xb[(size_t)m * HC + gc] = f2b(acc[mf][nfr][r]);
                }
        } else {
            const float bv = bias[gc - HC];
#pragma unroll
            for (int mf = 0; mf < 4; ++mf)
#pragma unroll
                for (int r = 0; r < 4; ++r) {
                    int m = n0 + mf * 16 + lk * 4 + r;
                    if (m < N_NODES) out[(size_t)m * HC + gc - HC] = acc[mf][nfr][r] + bv;
                }
        }
    }
}

// ---------------------------------------------------------------------------
// Kernel 1b: a_src/a_dst from bf16 x. One wave per node; lane holds 2 channels.
// ---------------------------------------------------------------------------
__global__ __launch_bounds__(256) void a_kernel(
    const unsigned int* __restrict__ xb32, const float* __restrict__ att_src,
    const float* __restrict__ att_dst, float* __restrict__ asrc,
    float* __restrict__ adst)
{
    const int wave = threadIdx.x >> 6, lane = threadIdx.x & 63;
    const int n = blockIdx.x * 4 + wave;
    if (n >= N_NODES) return;
    unsigned v = xb32[(size_t)n * 64 + lane];
    float x0 = b2f_lo(v), x1 = b2f_hi(v);
    float2 as = ((const float2*)att_src)[lane];
    float2 ad = ((const float2*)att_dst)[lane];
    float ps = x0 * as.x + x1 * as.y;
    float pd = x0 * ad.x + x1 * ad.y;
#pragma unroll
    for (int off = 1; off < 16; off <<= 1) {
        ps += __shfl_xor(ps, off);
        pd += __shfl_xor(pd, off);
    }
    if ((lane & 15) == 0) {
        asrc[(size_t)n * H_HEADS + (lane >> 4)] = ps;
        adst[(size_t)n * H_HEADS + (lane >> 4)] = pd;
    }
}

// ---------------------------------------------------------------------------
// CSR scan: 3-kernel exclusive scan over counts.
// ---------------------------------------------------------------------------
__global__ __launch_bounds__(256) void scan1_kernel(const int* __restrict__ counts,
                                                    int* __restrict__ row_ptr,
                                                    int* __restrict__ blocksum)
{
    __shared__ int s[256];
    int t = threadIdx.x;
    int i = blockIdx.x * 256 + t;
    int v = (i < N_NODES) ? counts[i] : 0;
    s[t] = v;
    __syncthreads();
#pragma unroll
    for (int off = 1; off < 256; off <<= 1) {
        int u = (t >= off) ? s[t - off] : 0;
        __syncthreads();
        s[t] += u;
        __syncthreads();
    }
    if (i < N_NODES) row_ptr[i] = s[t] - v;      // local exclusive prefix
    if (t == 255) blocksum[blockIdx.x] = s[255]; // block total
}

__global__ __launch_bounds__(256) void scan2_kernel(int* __restrict__ blocksum)
{
    __shared__ int s[256];
    int t = threadIdx.x;
    int v = (t < NB_SCAN) ? blocksum[t] : 0;
    s[t] = v;
    __syncthreads();
#pragma unroll
    for (int off = 1; off < 256; off <<= 1) {
        int u = (t >= off) ? s[t - off] : 0;
        __syncthreads();
        s[t] += u;
        __syncthreads();
    }
    blocksum[t] = s[t] - v;                       // exclusive block offsets
}

__global__ __launch_bounds__(256) void scan3_kernel(int* __restrict__ row_ptr,
                                                    const int* __restrict__ blocksum)
{
    int i = blockIdx.x * 256 + threadIdx.x;
    if (i < N_NODES) row_ptr[i] = row_ptr[i] + blocksum[blockIdx.x];
    if (i == 0) row_ptr[N_NODES] = (int)E_EDGES;
}

// ---------------------------------------------------------------------------
// Kernel 3a: per-edge logits, PURE STREAM (no scatter).  Thread-per-edge:
// ef read coalesced, asrc/adst gathers (L2-resident arrays), packed 16B
// record written coalesced in EDGE order.
// Packed record: word h = (fp32 bits of alpha_h & ~0xFF) | byte_h(src).
// ---------------------------------------------------------------------------
__global__ __launch_bounds__(256) void el_stream_kernel(
    const float* __restrict__ ef, const int* __restrict__ src,
    const int* __restrict__ dst, const float* __restrict__ weff,
    const float* __restrict__ asrc, const float* __restrict__ adst,
    uint4* __restrict__ rec_e)
{
    __shared__ float wf[128];
    const int t = threadIdx.x;
    if (t < 128) wf[t] = weff[t];
    __syncthreads();

    const long e = (long)blockIdx.x * 256 + t;
    if (e >= E_EDGES) return;

    const float4* ef4 = (const float4*)ef;
    float4 q[8];
#pragma unroll
    for (int j = 0; j < 8; ++j) q[j] = ef4[(size_t)e * 8 + j];

    const int s = src[e], d = dst[e];
    float4 as4 = ((const float4*)asrc)[s];
    float4 ad4 = ((const float4*)adst)[d];
    float base[4] = {as4.x + ad4.x, as4.y + ad4.y, as4.z + ad4.z, as4.w + ad4.w};

    uint4 r;
    unsigned* rw = (unsigned*)&r;
#pragma unroll
    for (int h = 0; h < 4; ++h) {
        float acc = 0.f;
#pragma unroll
        for (int f4 = 0; f4 < 8; ++f4) {
            float4 w4 = *(const float4*)&wf[h * 32 + f4 * 4];
            acc = fmaf(q[f4].x, w4.x, acc); acc = fmaf(q[f4].y, w4.y, acc);
            acc = fmaf(q[f4].z, w4.z, acc); acc = fmaf(q[f4].w, w4.w, acc);
        }
        float logit = base[h] + acc;
        float al = logit > 0.f ? logit : NEG_SLOPE * logit;
        rw[h] = (__float_as_uint(al) & 0xFFFFFF00u)
              | ((unsigned)(s >> (8 * h)) & 0xFFu);
    }
    rec_e[e] = r;
}

// ---------------------------------------------------------------------------
// Kernel 3b: scatter records to CSR (dst-sorted) order.  The 800K random
// 64B-line touches run isolated here, with nothing competing for DRAM.
// ---------------------------------------------------------------------------
__global__ __launch_bounds__(256) void scatter_kernel(
    const int* __restrict__ dst, const int* __restrict__ rank,
    const int* __restrict__ row_ptr, const uint4* __restrict__ rec_e,
    uint4* __restrict__ rec_s)
{
    const long e = (long)blockIdx.x * 256 + threadIdx.x;
    if (e < E_EDGES) {
        int d = dst[e];
        int pos = row_ptr[d] + rank[e];
        rec_s[pos] = rec_e[e];
    }
}

// ---------------------------------------------------------------------------
// Kernel 4: fused per-node aggregation, bf16 x gather.
// One wave per node; 16 lanes per edge (8 ch each), 4 edges per step,
// 2x unrolled (8 gathers in flight).  Fixed-shift softmax (no max pass).
// Reads one packed 16B record per edge: src from low bytes, alpha by head.
// ---------------------------------------------------------------------------
__device__ __forceinline__ void accum8(float* acc, uint4 v, float e) {
    acc[0] = fmaf(b2f_lo(v.x), e, acc[0]);
    acc[1] = fmaf(b2f_hi(v.x), e, acc[1]);
    acc[2] = fmaf(b2f_lo(v.y), e, acc[2]);
    acc[3] = fmaf(b2f_hi(v.y), e, acc[3]);
    acc[4] = fmaf(b2f_lo(v.z), e, acc[4]);
    acc[5] = fmaf(b2f_hi(v.z), e, acc[5]);
    acc[6] = fmaf(b2f_lo(v.w), e, acc[6]);
    acc[7] = fmaf(b2f_hi(v.w), e, acc[7]);
}

__device__ __forceinline__ int rec_src(uint4 r) {
    return (int)((r.x & 0xFFu) | ((r.y & 0xFFu) << 8));
}
__device__ __forceinline__ float rec_alpha(uint4 r, int h) {
    unsigned w = h == 0 ? r.x : h == 1 ? r.y : h == 2 ? r.z : r.w;
    return __uint_as_float(w & 0xFFFFFF00u);
}

__global__ __launch_bounds__(256) void aggregate_kernel(
    const int* __restrict__ row_ptr, const uint4* __restrict__ rec4,
    const uint4* __restrict__ xb4, float* __restrict__ out)
{
    const int wave = threadIdx.x >> 6;
    const int lane = threadIdx.x & 63;
    const int d = blockIdx.x * 4 + wave;
    if (d >= N_NODES) return;
    const int beg = row_ptr[d], end = row_ptr[d + 1];
    const int q  = lane >> 4;        // edge slot 0..3
    const int cg = lane & 15;        // channel group: ch 8*cg .. 8*cg+7
    const int h  = cg >> 2;          // head

    float acc[8] = {0.f, 0.f, 0.f, 0.f, 0.f, 0.f, 0.f, 0.f};
    float dsum = 0.f;

    int i = beg;
    for (; i + 8 <= end; i += 8) {           // both 4-edge groups fully valid
        int i0 = i + q, i1 = i + 4 + q;
        uint4 r0 = rec4[i0];
        uint4 r1 = rec4[i1];
        int s0 = rec_src(r0);
        int s1 = rec_src(r1);
        float a0 = rec_alpha(r0, h);
        float a1 = rec_alpha(r1, h);
        uint4 v0 = xb4[(size_t)s0 * 16 + cg];
        uint4 v1 = xb4[(size_t)s1 * 16 + cg];
        float e0 = __expf(a0 - SM_SHIFT);
        float e1 = __expf(a1 - SM_SHIFT);
        dsum += e0 + e1;
        accum8(acc, v0, e0);
        accum8(acc, v1, e1);
    }
    for (; i < end; i += 4) {                // masked tail
        int idx = i + q;
        bool val = idx < end;
        int ii = val ? idx : end - 1;
        uint4 r = rec4[ii];
        int s = rec_src(r);
        float a = rec_alpha(r, h);
        uint4 v = xb4[(size_t)s * 16 + cg];
        float e = val ? __expf(a - SM_SHIFT) : 0.f;
        dsum += e;
        accum8(acc, v, e);
    }

    // reduce over the 4 edge slots (lane bits 4,5)
#pragma unroll
    for (int off = 16; off <= 32; off <<= 1) {
        dsum += __shfl_xor(dsum, off);
#pragma unroll
        for (int k = 0; k < 8; ++k) acc[k] += __shfl_xor(acc[k], off);
    }
    const float inv = 1.f / (dsum + EPS);

    if (q == 0) {                            // 16 lanes cover the 128-ch row
        float* op = out + (size_t)d * HC + cg * 8;
        float4 o0 = *(const float4*)op;
        float4 o1 = *(const float4*)(op + 4);
        o0.x += acc[0] * inv; o0.y += acc[1] * inv;
        o0.z += acc[2] * inv; o0.w += acc[3] * inv;
        o1.x += acc[4] * inv; o1.y += acc[5] * inv;
        o1.z += acc[6] * inv; o1.w += acc[7] * inv;
        o0.x = o0.x > 0.f ? o0.x : expf(o0.x) - 1.f;   // ELU
        o0.y = o0.y > 0.f ? o0.y : expf(o0.y) - 1.f;
        o0.z = o0.z > 0.f ? o0.z : expf(o0.z) - 1.f;
        o0.w = o0.w > 0.f ? o0.w : expf(o0.w) - 1.f;
        o1.x = o1.x > 0.f ? o1.x : expf(o1.x) - 1.f;
        o1.y = o1.y > 0.f ? o1.y : expf(o1.y) - 1.f;
        o1.z = o1.z > 0.f ? o1.z : expf(o1.z) - 1.f;
        o1.w = o1.w > 0.f ? o1.w : expf(o1.w) - 1.f;
        *(float4*)op = o0;
        *(float4*)(op + 4) = o1;
    }
}

extern "C" void kernel_launch(void* const* d_in, const int* in_sizes, int n_in,
                              void* d_out, int out_size, void* d_ws, size_t ws_size,
                              hipStream_t stream)
{
    const float* nf       = (const float*)d_in[0];
    const float* ef       = (const float*)d_in[1];
    const int*   ei       = (const int*)d_in[2];   // [2,E]: src row 0, dst row 1
    const float* Wg       = (const float*)d_in[3];
    const float* att_src  = (const float*)d_in[4];
    const float* att_dst  = (const float*)d_in[5];
    const float* att_edge = (const float*)d_in[6];
    const float* bias     = (const float*)d_in[7];
    const float* We       = (const float*)d_in[8];
    const float* Ws       = (const float*)d_in[9];
    float* out = (float*)d_out;

    const int* src = ei;
    const int* dst = ei + E_EDGES;

    // workspace layout (16B-aligned sections first)
    unsigned int* rec_s = (unsigned int*)d_ws;                   // E*4 u32 (CSR order)
    unsigned int* rec_e = rec_s + 4 * E_EDGES;                   // E*4 u32 (edge order)
    unsigned short* xb  = (unsigned short*)(rec_e + 4 * E_EDGES); // N*128 bf16
    unsigned short* wcat= xb + (size_t)N_NODES * HC;             // 256*128 bf16
    float* asrc         = (float*)(wcat + 256 * 128);            // N*4
    float* adst         = asrc + (size_t)N_NODES * H_HEADS;      // N*4
    float* weff         = adst + (size_t)N_NODES * H_HEADS;      // 128
    int*   counts       = (int*)(weff + 128);                    // N
    int*   row_ptr      = counts + N_NODES;                      // N+1
    int*   blocksum     = row_ptr + N_NODES + 1;                 // 256
    int*   rank         = blocksum + 256;                        // E

    (void)hipMemsetAsync(counts, 0, (size_t)N_NODES * sizeof(int), stream);

    prep_kernel<<<33 + NB_HIST, 256, 0, stream>>>(
        Wg, Ws, wcat, We, att_edge, weff, dst, counts, rank);
    mfma_gemm_kernel<<<(N_NODES + 63) / 64, 256, 0, stream>>>(
        nf, wcat, bias, xb, out);
    a_kernel<<<(N_NODES + 3) / 4, 256, 0, stream>>>(
        (const unsigned int*)xb, att_src, att_dst, asrc, adst);
    scan1_kernel<<<NB_SCAN, 256, 0, stream>>>(counts, row_ptr, blocksum);
    scan2_kernel<<<1, 256, 0, stream>>>(blocksum);
    scan3_kernel<<<NB_SCAN, 256, 0, stream>>>(row_ptr, blocksum);
    el_stream_kernel<<<NB_HIST, 256, 0, stream>>>(
        ef, src, dst, weff, asrc, adst, (uint4*)rec_e);
    scatter_kernel<<<NB_HIST, 256, 0, stream>>>(
        dst, rank, row_ptr, (const uint4*)rec_e, (uint4*)rec_s);
    aggregate_kernel<<<(N_NODES + 3) / 4, 256, 0, stream>>>(
        row_ptr, (const uint4*)rec_s, (const uint4*)xb, out);
}

// Round 4
// 175.397 us; speedup vs baseline: 1.0834x; 1.0834x over previous
//
#include <hip/hip_runtime.h>
#include <hip/hip_bf16.h>

// Problem constants (fixed by the reference).
constexpr int N_NODES = 50000;
constexpr int IN_F    = 128;
constexpr long E_EDGES = 800000;
constexpr int EDGE_F  = 32;
constexpr int H_HEADS = 4;
constexpr int C_CH    = 32;
constexpr int HC      = 128;   // H*C
constexpr float NEG_SLOPE = 0.2f;
constexpr float EPS = 1e-16f;
constexpr int NB_SCAN = (N_NODES + 255) / 256;   // 196
constexpr int NB_HIST = (int)((E_EDGES + 255) / 256); // 3125
constexpr float SM_SHIFT = 12.0f;  // fixed softmax shift (shift-invariant; logits << 87)

typedef __attribute__((ext_vector_type(8))) short bf16x8;
typedef __attribute__((ext_vector_type(4))) float f32x4;

__device__ __forceinline__ unsigned short f2b(float f) {
    __hip_bfloat16 h = __float2bfloat16(f);   // RNE
    return *reinterpret_cast<unsigned short*>(&h);
}
__device__ __forceinline__ float b2f_lo(unsigned v) { return __uint_as_float(v << 16); }
__device__ __forceinline__ float b2f_hi(unsigned v) { return __uint_as_float(v & 0xffff0000u); }

// ---------------------------------------------------------------------------
// zero kernel: replaces hipMemsetAsync(counts) — the runtime's
// fillBufferAligned kernel measured 58 µs for 200 KB under graph replay.
// ---------------------------------------------------------------------------
__global__ __launch_bounds__(256) void zero_counts_kernel(int* __restrict__ counts)
{
    int i = blockIdx.x * 256 + threadIdx.x;
    if (i < N_NODES) counts[i] = 0;
}

// ---------------------------------------------------------------------------
// prep kernel: blocks 0..31 convert W_gat/W_skip -> wcat bf16 [256][128];
// block 32 computes weff[h,f] = sum_c W_edge[h*32+c,f]*att_edge[h,c];
// blocks 33.. histogram dst -> counts AND record per-edge rank (return value).
// The contended atomic pass is paid exactly once, here.
// ---------------------------------------------------------------------------
__global__ __launch_bounds__(256) void prep_kernel(
    const float* __restrict__ Wg, const float* __restrict__ Ws,
    unsigned short* __restrict__ wcat, const float* __restrict__ We,
    const float* __restrict__ att_edge, float* __restrict__ weff,
    const int* __restrict__ dst, int* __restrict__ counts,
    int* __restrict__ rank)
{
    const int b = blockIdx.x, t = threadIdx.x;
    if (b < 32) {
        int i = (b * 256 + t) * 4;   // 0 .. 32764
        const float* srcp = (i < 16384) ? (Wg + i) : (Ws + i - 16384);
        float4 v = *(const float4*)srcp;
        ushort4 o;
        o.x = f2b(v.x); o.y = f2b(v.y); o.z = f2b(v.z); o.w = f2b(v.w);
        *(ushort4*)&wcat[i] = o;
    } else if (b == 32) {
        if (t < 128) {
            int h = t >> 5, f = t & 31;
            float acc = 0.f;
#pragma unroll
            for (int c = 0; c < C_CH; ++c)
                acc = fmaf(We[(h * C_CH + c) * EDGE_F + f], att_edge[h * C_CH + c], acc);
            weff[t] = acc;
        }
    } else {
        long e = (long)(b - 33) * 256 + t;
        if (e < E_EDGES) rank[e] = atomicAdd(&counts[dst[e]], 1);
    }
}

// ---------------------------------------------------------------------------
// Kernel 1: MFMA GEMM.  [N x 128] @ [256 x 128]^T; cols 0..127 -> x (bf16),
// cols 128..255 -> out (+bias, fp32).  Block: 64 nodes x 256 cols, 4 waves,
// wave w owns cols w*64..w*64+63.  No LDS, no barriers; B held in VGPRs;
// A read fp32 from nf and converted in-register.
// ---------------------------------------------------------------------------
__global__ __launch_bounds__(256) void mfma_gemm_kernel(
    const float* __restrict__ nf, const unsigned short* __restrict__ wcat,
    const float* __restrict__ bias, unsigned short* __restrict__ xb,
    float* __restrict__ out)
{
    const int t  = threadIdx.x;
    const int w  = t >> 6;          // wave id: cols w*64 ..
    const int l  = t & 63;
    const int lr = l & 15;
    const int lk = l >> 4;
    const int n0 = blockIdx.x * 64;

    // B frags: 4 col-frags x 4 k-steps, 16B each -> 64 VGPRs
    bf16x8 bfr[4][4];
#pragma unroll
    for (int nfr = 0; nfr < 4; ++nfr)
#pragma unroll
        for (int ks = 0; ks < 4; ++ks)
            bfr[nfr][ks] = *(const bf16x8*)&wcat[(w * 64 + nfr * 16 + lr) * 128 + ks * 32 + lk * 8];

    f32x4 acc[4][4];
#pragma unroll
    for (int mf = 0; mf < 4; ++mf)
#pragma unroll
        for (int nfr = 0; nfr < 4; ++nfr)
            acc[mf][nfr] = (f32x4){0.f, 0.f, 0.f, 0.f};

#pragma unroll
    for (int ks = 0; ks < 4; ++ks) {
        bf16x8 afr[4];
#pragma unroll
        for (int mf = 0; mf < 4; ++mf) {
            int row = n0 + mf * 16 + lr;
            row = row < N_NODES ? row : N_NODES - 1;   // clamp (tail rows discarded)
            const float* ap = nf + (size_t)row * IN_F + ks * 32 + lk * 8;
            float4 a0 = *(const float4*)ap;
            float4 a1 = *(const float4*)(ap + 4);
            bf16x8 f;
            f[0] = (short)f2b(a0.x); f[1] = (short)f2b(a0.y);
            f[2] = (short)f2b(a0.z); f[3] = (short)f2b(a0.w);
            f[4] = (short)f2b(a1.x); f[5] = (short)f2b(a1.y);
            f[6] = (short)f2b(a1.z); f[7] = (short)f2b(a1.w);
            afr[mf] = f;
        }
#pragma unroll
        for (int mf = 0; mf < 4; ++mf)
#pragma unroll
            for (int nfr = 0; nfr < 4; ++nfr)
                acc[mf][nfr] = __builtin_amdgcn_mfma_f32_16x16x32_bf16(
                    afr[mf], bfr[nfr][ks], acc[mf][nfr], 0, 0, 0);
    }

    // epilogue: cols <128 -> x (bf16) ; cols >=128 -> out + bias (fp32)
#pragma unroll
    for (int nfr = 0; nfr < 4; ++nfr) {
        const int gc = w * 64 + nfr * 16 + lr;
        if (gc < HC) {
#pragma unroll
            for (int mf = 0; mf < 4; ++mf)
#pragma unroll
                for (int r = 0; r < 4; ++r) {
                    int m = n0 + mf * 16 + lk * 4 + r;
                    if (m < N_NODES) xb[(size_t)m * HC + gc] = f2b(acc[mf][nfr][r]);
                }
        } else {
            const float bv = bias[gc - HC];
#pragma unroll
            for (int mf = 0; mf < 4; ++mf)
#pragma unroll
                for (int r = 0; r < 4; ++r) {
                    int m = n0 + mf * 16 + lk * 4 + r;
                    if (m < N_NODES) out[(size_t)m * HC + gc - HC] = acc[mf][nfr][r] + bv;
                }
        }
    }
}

// ---------------------------------------------------------------------------
// Kernel 1b: a_src/a_dst from bf16 x. One wave per node; lane holds 2 channels.
// ---------------------------------------------------------------------------
__global__ __launch_bounds__(256) void a_kernel(
    const unsigned int* __restrict__ xb32, const float* __restrict__ att_src,
    const float* __restrict__ att_dst, float* __restrict__ asrc,
    float* __restrict__ adst)
{
    const int wave = threadIdx.x >> 6, lane = threadIdx.x & 63;
    const int n = blockIdx.x * 4 + wave;
    if (n >= N_NODES) return;
    unsigned v = xb32[(size_t)n * 64 + lane];
    float x0 = b2f_lo(v), x1 = b2f_hi(v);
    float2 as = ((const float2*)att_src)[lane];
    float2 ad = ((const float2*)att_dst)[lane];
    float ps = x0 * as.x + x1 * as.y;
    float pd = x0 * ad.x + x1 * ad.y;
#pragma unroll
    for (int off = 1; off < 16; off <<= 1) {
        ps += __shfl_xor(ps, off);
        pd += __shfl_xor(pd, off);
    }
    if ((lane & 15) == 0) {
        asrc[(size_t)n * H_HEADS + (lane >> 4)] = ps;
        adst[(size_t)n * H_HEADS + (lane >> 4)] = pd;
    }
}

// ---------------------------------------------------------------------------
// CSR scan: 3-kernel exclusive scan over counts.
// ---------------------------------------------------------------------------
__global__ __launch_bounds__(256) void scan1_kernel(const int* __restrict__ counts,
                                                    int* __restrict__ row_ptr,
                                                    int* __restrict__ blocksum)
{
    __shared__ int s[256];
    int t = threadIdx.x;
    int i = blockIdx.x * 256 + t;
    int v = (i < N_NODES) ? counts[i] : 0;
    s[t] = v;
    __syncthreads();
#pragma unroll
    for (int off = 1; off < 256; off <<= 1) {
        int u = (t >= off) ? s[t - off] : 0;
        __syncthreads();
        s[t] += u;
        __syncthreads();
    }
    if (i < N_NODES) row_ptr[i] = s[t] - v;      // local exclusive prefix
    if (t == 255) blocksum[blockIdx.x] = s[255]; // block total
}

__global__ __launch_bounds__(256) void scan2_kernel(int* __restrict__ blocksum)
{
    __shared__ int s[256];
    int t = threadIdx.x;
    int v = (t < NB_SCAN) ? blocksum[t] : 0;
    s[t] = v;
    __syncthreads();
#pragma unroll
    for (int off = 1; off < 256; off <<= 1) {
        int u = (t >= off) ? s[t - off] : 0;
        __syncthreads();
        s[t] += u;
        __syncthreads();
    }
    blocksum[t] = s[t] - v;                       // exclusive block offsets
}

__global__ __launch_bounds__(256) void scan3_kernel(int* __restrict__ row_ptr,
                                                    const int* __restrict__ blocksum)
{
    int i = blockIdx.x * 256 + threadIdx.x;
    if (i < N_NODES) row_ptr[i] = row_ptr[i] + blocksum[blockIdx.x];
    if (i == 0) row_ptr[N_NODES] = (int)E_EDGES;
}

// ---------------------------------------------------------------------------
// Kernel 3: per-edge logits + leaky relu, written to CSR (dst-sorted) position.
// NO atomics: pos = row_ptr[dst] + rank[e] (rank assigned during histogram).
// Packed record: word h = (fp32 bits of alpha_h & ~0xFF) | byte_h(src).
// src < 2^16 so bytes 2,3 are zero; alpha loses 8 mantissa bits (rel err 2^-15).
// The 4 head lanes store 4 contiguous dwords -> one 16B line-touch per edge.
// ---------------------------------------------------------------------------
__global__ __launch_bounds__(256) void edge_logits_kernel(
    const float* __restrict__ ef, const int* __restrict__ src,
    const int* __restrict__ dst, const float* __restrict__ weff,
    const float* __restrict__ asrc, const float* __restrict__ adst,
    const int* __restrict__ row_ptr, const int* __restrict__ rank,
    unsigned int* __restrict__ rec)
{
    __shared__ float ef_lds[64][36];
    __shared__ float wf[4][36];
    const int t = threadIdx.x;
    const long e0 = (long)blockIdx.x * 64;

    // stage 64 edges x 32 feats = 512 float4, 2 per thread (coalesced)
#pragma unroll
    for (int j = 0; j < 2; ++j) {
        int i4 = t + j * 256;                 // 0..511
        int el = i4 >> 3, f4 = i4 & 7;
        long e = e0 + el;
        float4 v = (e < E_EDGES) ? ((const float4*)ef)[e * 8 + f4]
                                 : make_float4(0.f, 0.f, 0.f, 0.f);
        ef_lds[el][f4 * 4 + 0] = v.x; ef_lds[el][f4 * 4 + 1] = v.y;
        ef_lds[el][f4 * 4 + 2] = v.z; ef_lds[el][f4 * 4 + 3] = v.w;
    }
    if (t < 128) wf[t >> 5][t & 31] = weff[t];
    __syncthreads();

    const int el = t >> 2, h = t & 3;
    const long e = e0 + el;
    if (e < E_EDGES) {
        float acc = 0.f;
#pragma unroll
        for (int f4 = 0; f4 < 8; ++f4) {
            float4 a = *(const float4*)&ef_lds[el][f4 * 4];
            float4 b = *(const float4*)&wf[h][f4 * 4];
            acc = fmaf(a.x, b.x, acc); acc = fmaf(a.y, b.y, acc);
            acc = fmaf(a.z, b.z, acc); acc = fmaf(a.w, b.w, acc);
        }
        int s = src[e], d = dst[e];
        float logit = asrc[(size_t)s * H_HEADS + h] + adst[(size_t)d * H_HEADS + h] + acc;
        float al = logit > 0.f ? logit : NEG_SLOPE * logit;
        int pos = row_ptr[d] + rank[e];
        unsigned w = (__float_as_uint(al) & 0xFFFFFF00u)
                   | ((unsigned)(s >> (8 * h)) & 0xFFu);
        rec[(size_t)pos * 4 + h] = w;
    }
}

// ---------------------------------------------------------------------------
// Kernel 4: fused per-node aggregation, bf16 x gather.
// One wave per node; 16 lanes per edge (8 ch each), 4 edges per step,
// 2x unrolled (8 gathers in flight).  Fixed-shift softmax (no max pass).
// Reads one packed 16B record per edge: src from low bytes, alpha by head.
// ---------------------------------------------------------------------------
__device__ __forceinline__ void accum8(float* acc, uint4 v, float e) {
    acc[0] = fmaf(b2f_lo(v.x), e, acc[0]);
    acc[1] = fmaf(b2f_hi(v.x), e, acc[1]);
    acc[2] = fmaf(b2f_lo(v.y), e, acc[2]);
    acc[3] = fmaf(b2f_hi(v.y), e, acc[3]);
    acc[4] = fmaf(b2f_lo(v.z), e, acc[4]);
    acc[5] = fmaf(b2f_hi(v.z), e, acc[5]);
    acc[6] = fmaf(b2f_lo(v.w), e, acc[6]);
    acc[7] = fmaf(b2f_hi(v.w), e, acc[7]);
}

__device__ __forceinline__ int rec_src(uint4 r) {
    return (int)((r.x & 0xFFu) | ((r.y & 0xFFu) << 8));
}
__device__ __forceinline__ float rec_alpha(uint4 r, int h) {
    unsigned w = h == 0 ? r.x : h == 1 ? r.y : h == 2 ? r.z : r.w;
    return __uint_as_float(w & 0xFFFFFF00u);
}

__global__ __launch_bounds__(256) void aggregate_kernel(
    const int* __restrict__ row_ptr, const uint4* __restrict__ rec4,
    const uint4* __restrict__ xb4, float* __restrict__ out)
{
    const int wave = threadIdx.x >> 6;
    const int lane = threadIdx.x & 63;
    const int d = blockIdx.x * 4 + wave;
    if (d >= N_NODES) return;
    const int beg = row_ptr[d], end = row_ptr[d + 1];
    const int q  = lane >> 4;        // edge slot 0..3
    const int cg = lane & 15;        // channel group: ch 8*cg .. 8*cg+7
    const int h  = cg >> 2;          // head

    float acc[8] = {0.f, 0.f, 0.f, 0.f, 0.f, 0.f, 0.f, 0.f};
    float dsum = 0.f;

    int i = beg;
    for (; i + 8 <= end; i += 8) {           // both 4-edge groups fully valid
        int i0 = i + q, i1 = i + 4 + q;
        uint4 r0 = rec4[i0];
        uint4 r1 = rec4[i1];
        int s0 = rec_src(r0);
        int s1 = rec_src(r1);
        float a0 = rec_alpha(r0, h);
        float a1 = rec_alpha(r1, h);
        uint4 v0 = xb4[(size_t)s0 * 16 + cg];
        uint4 v1 = xb4[(size_t)s1 * 16 + cg];
        float e0 = __expf(a0 - SM_SHIFT);
        float e1 = __expf(a1 - SM_SHIFT);
        dsum += e0 + e1;
        accum8(acc, v0, e0);
        accum8(acc, v1, e1);
    }
    for (; i < end; i += 4) {                // masked tail
        int idx = i + q;
        bool val = idx < end;
        int ii = val ? idx : end - 1;
        uint4 r = rec4[ii];
        int s = rec_src(r);
        float a = rec_alpha(r, h);
        uint4 v = xb4[(size_t)s * 16 + cg];
        float e = val ? __expf(a - SM_SHIFT) : 0.f;
        dsum += e;
        accum8(acc, v, e);
    }

    // reduce over the 4 edge slots (lane bits 4,5)
#pragma unroll
    for (int off = 16; off <= 32; off <<= 1) {
        dsum += __shfl_xor(dsum, off);
#pragma unroll
        for (int k = 0; k < 8; ++k) acc[k] += __shfl_xor(acc[k], off);
    }
    const float inv = 1.f / (dsum + EPS);

    if (q == 0) {                            // 16 lanes cover the 128-ch row
        float* op = out + (size_t)d * HC + cg * 8;
        float4 o0 = *(const float4*)op;
        float4 o1 = *(const float4*)(op + 4);
        o0.x += acc[0] * inv; o0.y += acc[1] * inv;
        o0.z += acc[2] * inv; o0.w += acc[3] * inv;
        o1.x += acc[4] * inv; o1.y += acc[5] * inv;
        o1.z += acc[6] * inv; o1.w += acc[7] * inv;
        o0.x = o0.x > 0.f ? o0.x : expf(o0.x) - 1.f;   // ELU
        o0.y = o0.y > 0.f ? o0.y : expf(o0.y) - 1.f;
        o0.z = o0.z > 0.f ? o0.z : expf(o0.z) - 1.f;
        o0.w = o0.w > 0.f ? o0.w : expf(o0.w) - 1.f;
        o1.x = o1.x > 0.f ? o1.x : expf(o1.x) - 1.f;
        o1.y = o1.y > 0.f ? o1.y : expf(o1.y) - 1.f;
        o1.z = o1.z > 0.f ? o1.z : expf(o1.z) - 1.f;
        o1.w = o1.w > 0.f ? o1.w : expf(o1.w) - 1.f;
        *(float4*)op = o0;
        *(float4*)(op + 4) = o1;
    }
}

extern "C" void kernel_launch(void* const* d_in, const int* in_sizes, int n_in,
                              void* d_out, int out_size, void* d_ws, size_t ws_size,
                              hipStream_t stream)
{
    const float* nf       = (const float*)d_in[0];
    const float* ef       = (const float*)d_in[1];
    const int*   ei       = (const int*)d_in[2];   // [2,E]: src row 0, dst row 1
    const float* Wg       = (const float*)d_in[3];
    const float* att_src  = (const float*)d_in[4];
    const float* att_dst  = (const float*)d_in[5];
    const float* att_edge = (const float*)d_in[6];
    const float* bias     = (const float*)d_in[7];
    const float* We       = (const float*)d_in[8];
    const float* Ws       = (const float*)d_in[9];
    float* out = (float*)d_out;

    const int* src = ei;
    const int* dst = ei + E_EDGES;

    // workspace layout (16B-aligned sections first)
    unsigned int* rec   = (unsigned int*)d_ws;                   // E*4 u32 (packed alpha|src)
    unsigned short* xb  = (unsigned short*)(rec + 4 * E_EDGES);  // N*128 bf16
    unsigned short* wcat= xb + (size_t)N_NODES * HC;             // 256*128 bf16
    float* asrc         = (float*)(wcat + 256 * 128);            // N*4
    float* adst         = asrc + (size_t)N_NODES * H_HEADS;      // N*4
    float* weff         = adst + (size_t)N_NODES * H_HEADS;      // 128
    int*   counts       = (int*)(weff + 128);                    // N
    int*   row_ptr      = counts + N_NODES;                      // N+1
    int*   blocksum     = row_ptr + N_NODES + 1;                 // 256
    int*   rank         = blocksum + 256;                        // E

    zero_counts_kernel<<<NB_SCAN, 256, 0, stream>>>(counts);
    prep_kernel<<<33 + NB_HIST, 256, 0, stream>>>(
        Wg, Ws, wcat, We, att_edge, weff, dst, counts, rank);
    mfma_gemm_kernel<<<(N_NODES + 63) / 64, 256, 0, stream>>>(
        nf, wcat, bias, xb, out);
    a_kernel<<<(N_NODES + 3) / 4, 256, 0, stream>>>(
        (const unsigned int*)xb, att_src, att_dst, asrc, adst);
    scan1_kernel<<<NB_SCAN, 256, 0, stream>>>(counts, row_ptr, blocksum);
    scan2_kernel<<<1, 256, 0, stream>>>(blocksum);
    scan3_kernel<<<NB_SCAN, 256, 0, stream>>>(row_ptr, blocksum);
    edge_logits_kernel<<<(int)(E_EDGES / 64), 256, 0, stream>>>(
        ef, src, dst, weff, asrc, adst, row_ptr, rank, rec);
    aggregate_kernel<<<(N_NODES + 3) / 4, 256, 0, stream>>>(
        row_ptr, (const uint4*)rec, (const uint4*)xb, out);
}